// Round 14
// baseline (228.760 us; speedup 1.0000x reference)
//
#include <hip/hip_runtime.h>
#include <hip/hip_bf16.h>

typedef short v8s __attribute__((ext_vector_type(8)));
typedef float v4f __attribute__((ext_vector_type(4)));

#define MFMA16(a, b, c) __builtin_amdgcn_mfma_f32_16x16x32_bf16((a), (b), (c), 0, 0, 0)

typedef __attribute__((address_space(1))) const void g_void;
typedef __attribute__((address_space(3))) void lds_void;
#define GLOAD_LDS16(g, l) \
    __builtin_amdgcn_global_load_lds((g_void*)(g), (lds_void*)(l), 16, 0, 0)

constexpr int Bsz   = 128;
constexpr int Lq    = 32;
constexpr int Ld    = 512;
constexpr int H     = 768;
constexpr int D     = 128;
constexpr int QROWS = Bsz * Lq;          // 4096
constexpr int DROWS = Bsz * Ld;          // 65536
constexpr int MTOT  = QROWS + 2 * DROWS; // 135168
constexpr int NKT   = 24;                // K-steps of 32
static_assert(QROWS % 128 == 0 && DROWS % 128 == 0, "blocks never span sources");

// f32 -> bf16 bits, round-to-nearest-even
static __device__ __forceinline__ unsigned short f2b(float f) {
    unsigned int u = __builtin_bit_cast(unsigned int, f);
    unsigned int r = u + 0x7FFFu + ((u >> 16) & 1u);
    return (unsigned short)(r >> 16);
}
static __device__ __forceinline__ v8s mk8(float4 f0, float4 f1) {
    v8s a;
    a[0] = (short)f2b(f0.x); a[1] = (short)f2b(f0.y);
    a[2] = (short)f2b(f0.z); a[3] = (short)f2b(f0.w);
    a[4] = (short)f2b(f1.x); a[5] = (short)f2b(f1.y);
    a[6] = (short)f2b(f1.z); a[7] = (short)f2b(f1.w);
    return a;
}

// ---------------------------------------------------------------------------
// Kernel 1: Wt[d][h] = bf16(W[h][d])
// ---------------------------------------------------------------------------
__global__ void prep_w_kernel(const float* __restrict__ W,
                              unsigned short* __restrict__ Wt) {
    int idx = blockIdx.x * 256 + threadIdx.x;
    if (idx < H * D) {
        int d = idx / H, h = idx % H;
        Wt[idx] = f2b(W[h * D + d]);
    }
}

// ---------------------------------------------------------------------------
// Kernel 2: projection — BARRIER-FREE per-wave pipeline.
//   4 waves/block, each fully independent: 32 rows x full D=128, K streamed
//   in 24 steps of 32. A: private per-wave LDS ring (3 x 4 KB) fed by
//   global_load_lds (own-wave vmcnt => no barrier needed for visibility);
//   issued 3 steps ahead. W: 8 v8s register loads/step from L2-hot Wt,
//   2 slots, issued 2 steps ahead. Fixed per-wave FIFO
//   [W(t),A(t),W(t+1),A(t+1),A(t+2)] -> s_waitcnt vmcnt(16) steady
//   (12, 0 at tail). ZERO s_barrier/syncthreads in the kernel.
//   sched_barrier(0) pins issue order (rule 18).
//   DMA swizzle (R11-verified, 0 conflicts): instr i covers rows 8i..8i+7;
//   lane l -> row 8i+(l>>3), chunk (l&7)^(l>>3); read chunk c^(r&7).
// ---------------------------------------------------------------------------
__global__ __launch_bounds__(256, 3) void proj_norm_kernel(
    const float* __restrict__ qh, const float* __restrict__ pdh,
    const float* __restrict__ ndh, const float* __restrict__ bias,
    const int* __restrict__ pdm, const int* __restrict__ ndm,
    const unsigned short* __restrict__ Wt, unsigned short* __restrict__ emb)
{
    __shared__ float Abuf[4][3][32 * 32];   // [wave][ring][tile] = 48 KB

    const int tid  = threadIdx.x;
    const int lane = tid & 63, wave = tid >> 6;
    const int l15  = lane & 15, lg = lane >> 4;
    const long row0w = (long)blockIdx.x * 128 + wave * 32;

    const float* src; const int* mask; long srow;
    if (row0w < QROWS)              { src = qh;  srow = row0w;                 mask = nullptr; }
    else if (row0w < QROWS + DROWS) { src = pdh; srow = row0w - QROWS;         mask = pdm; }
    else                            { src = ndh; srow = row0w - QROWS - DROWS; mask = ndm; }

    // A-DMA addressing: instr i, lane l -> row 8i+(l>>3), 16B chunk (l&7)^(l>>3)
    const int rdma = lane >> 3;
    const int cdma = (lane & 7) ^ rdma;
    const float* gA = src + (srow + rdma) * (long)H + cdma * 4;

    // W: fragment (nt, step kt) at Wt[(nt*16+l15)*H + kt*32 + lg*8]
    const unsigned short* wp = Wt + (size_t)l15 * H + lg * 8;

    v8s wa[8], wb[8];
    v4f acc[2][8];
#pragma unroll
    for (int m = 0; m < 2; ++m)
#pragma unroll
        for (int nt = 0; nt < 8; ++nt) acc[m][nt] = (v4f){0.f, 0.f, 0.f, 0.f};

#define STAGE(BI, KT)                                                       \
    {                                                                       \
        _Pragma("unroll")                                                   \
        for (int i_ = 0; i_ < 4; ++i_)                                      \
            GLOAD_LDS16(gA + (size_t)(8 * i_) * H + (KT) * 32,              \
                        &Abuf[wave][BI][i_ * 256]);                         \
    }

#define ISSW(S, KT)                                                         \
    {                                                                       \
        _Pragma("unroll")                                                   \
        for (int nt_ = 0; nt_ < 8; ++nt_)                                   \
            w##S[nt_] = *(const v8s*)(wp + (size_t)nt_ * 16 * H + (KT) * 32);\
    }

#define CMP(BI, S)                                                          \
    {                                                                       \
        _Pragma("unroll")                                                   \
        for (int m_ = 0; m_ < 2; ++m_) {                                    \
            const int r_  = m_ * 16 + l15;                                  \
            const int c0_ = (2 * lg)     ^ (r_ & 7);                        \
            const int c1_ = (2 * lg + 1) ^ (r_ & 7);                        \
            float4 f0_ = *(const float4*)(&Abuf[wave][BI][r_ * 32 + c0_ * 4]);\
            float4 f1_ = *(const float4*)(&Abuf[wave][BI][r_ * 32 + c1_ * 4]);\
            v8s a_ = mk8(f0_, f1_);                                         \
            _Pragma("unroll")                                               \
            for (int nt_ = 0; nt_ < 8; ++nt_)                               \
                acc[m_][nt_] = MFMA16(a_, w##S[nt_], acc[m_][nt_]);         \
        }                                                                   \
    }

#define STEP(T, BI, S, VM)                                                  \
    asm volatile("s_waitcnt vmcnt(" #VM ")" ::: "memory");                  \
    __builtin_amdgcn_sched_barrier(0);                                      \
    CMP(BI, S)                                                              \
    asm volatile("s_waitcnt lgkmcnt(0)" ::: "memory");                      \
    __builtin_amdgcn_sched_barrier(0);                                      \
    if ((T) + 2 < NKT) { ISSW(S, (T) + 2) }                                 \
    __builtin_amdgcn_sched_barrier(0);                                      \
    if ((T) + 3 < NKT) { STAGE(BI, (T) + 3) }                               \
    __builtin_amdgcn_sched_barrier(0);

    // prologue FIFO: [Wa(0)x8, A(0)x4, Wb(1)x8, A(1)x4, A(2)x4] = 28
    ISSW(a, 0)
    STAGE(0, 0)
    ISSW(b, 1)
    STAGE(1, 1)
    STAGE(2, 2)

    STEP(0, 0, a, 16)  STEP(1, 1, b, 16)  STEP(2, 2, a, 16)  STEP(3, 0, b, 16)
    STEP(4, 1, a, 16)  STEP(5, 2, b, 16)  STEP(6, 0, a, 16)  STEP(7, 1, b, 16)
    STEP(8, 2, a, 16)  STEP(9, 0, b, 16)  STEP(10, 1, a, 16) STEP(11, 2, b, 16)
    STEP(12, 0, a, 16) STEP(13, 1, b, 16) STEP(14, 2, a, 16) STEP(15, 0, b, 16)
    STEP(16, 1, a, 16) STEP(17, 2, b, 16) STEP(18, 0, a, 16) STEP(19, 1, b, 16)
    STEP(20, 2, a, 16) STEP(21, 0, b, 16) STEP(22, 1, a, 12) STEP(23, 2, b, 0)

#undef STEP
#undef CMP
#undef ISSW
#undef STAGE

    // ---- epilogue (per-wave, no sync): bias, in-wave L2-norm, mask, store
    float bv[8];
#pragma unroll
    for (int nt = 0; nt < 8; ++nt) bv[nt] = bias[nt * 16 + l15];

#pragma unroll
    for (int m = 0; m < 2; ++m) {
        float ss[4] = {0.f, 0.f, 0.f, 0.f};
#pragma unroll
        for (int nt = 0; nt < 8; ++nt)
#pragma unroll
            for (int q = 0; q < 4; ++q) {
                float v = acc[m][nt][q] + bv[nt];
                acc[m][nt][q] = v;
                ss[q] += v * v;
            }
#pragma unroll
        for (int off = 1; off < 16; off <<= 1)
#pragma unroll
            for (int q = 0; q < 4; ++q)
                ss[q] += __shfl_xor(ss[q], off);

#pragma unroll
        for (int q = 0; q < 4; ++q) {
            const int row = m * 16 + lg * 4 + q;
            float s = 1.0f / fmaxf(sqrtf(ss[q]), 1e-12f);
            if (mask) s *= (float)mask[srow + row];
            unsigned short* op = emb + (size_t)(row0w + row) * D + l15;
#pragma unroll
            for (int nt = 0; nt < 8; ++nt)
                op[nt * 16] = f2b(acc[m][nt][q] * s);
        }
    }
}

// ---------------------------------------------------------------------------
// Kernel 3: MaxSim. One block per (batch, side); 4 waves x 128 doc tokens.
// ---------------------------------------------------------------------------
__global__ __launch_bounds__(256) void maxsim_kernel(
    const unsigned short* __restrict__ emb, float* __restrict__ out)
{
    const int blk  = blockIdx.x;       // 0..255
    const int b    = blk >> 1, side = blk & 1;
    const int wave = threadIdx.x >> 6, lane = threadIdx.x & 63;
    const int l15  = lane & 15, lg = lane >> 4;

    const unsigned short* Q  = emb + (size_t)(b * Lq) * D;
    const unsigned short* Dm = emb + (size_t)(QROWS + side * DROWS + b * Ld) * D;

    v4f acc[2][8];
#pragma unroll
    for (int m = 0; m < 2; ++m)
#pragma unroll
        for (int n = 0; n < 8; ++n) acc[m][n] = (v4f){0.f, 0.f, 0.f, 0.f};

    const int tok0 = wave * 128;
#pragma unroll
    for (int kk = 0; kk < 4; ++kk) {
        const int k0 = kk * 32 + lg * 8;
        v8s qa0 = *(const v8s*)(Q + (size_t)(l15) * D + k0);
        v8s qa1 = *(const v8s*)(Q + (size_t)(16 + l15) * D + k0);
#pragma unroll
        for (int n = 0; n < 8; ++n) {
            v8s db = *(const v8s*)(Dm + (size_t)(tok0 + n * 16 + l15) * D + k0);
            acc[0][n] = MFMA16(qa0, db, acc[0][n]);
            acc[1][n] = MFMA16(qa1, db, acc[1][n]);
        }
    }

    float mx[2][4];
#pragma unroll
    for (int m = 0; m < 2; ++m)
#pragma unroll
        for (int r = 0; r < 4; ++r) {
            float v = acc[m][0][r];
#pragma unroll
            for (int n = 1; n < 8; ++n) v = fmaxf(v, acc[m][n][r]);
            mx[m][r] = v;
        }
#pragma unroll
    for (int off = 1; off < 16; off <<= 1) {
#pragma unroll
        for (int m = 0; m < 2; ++m)
#pragma unroll
            for (int r = 0; r < 4; ++r)
                mx[m][r] = fmaxf(mx[m][r], __shfl_xor(mx[m][r], off));
    }

    __shared__ float red[4][32];
    if (l15 == 0) {
#pragma unroll
        for (int m = 0; m < 2; ++m)
#pragma unroll
            for (int r = 0; r < 4; ++r)
                red[wave][m * 16 + lg * 4 + r] = mx[m][r];
    }
    __syncthreads();

    if (threadIdx.x < 32) {
        int q = threadIdx.x;
        float v = fmaxf(fmaxf(red[0][q], red[1][q]), fmaxf(red[2][q], red[3][q]));
#pragma unroll
        for (int off = 1; off < 32; off <<= 1) v += __shfl_xor(v, off);
        if (q == 0) out[blk] = v;
    }
}

// ---------------------------------------------------------------------------
extern "C" void kernel_launch(void* const* d_in, const int* in_sizes, int n_in,
                              void* d_out, int out_size, void* d_ws, size_t ws_size,
                              hipStream_t stream)
{
    const float* qh   = (const float*)d_in[0];
    const float* pdh  = (const float*)d_in[1];
    const float* ndh  = (const float*)d_in[2];
    const float* W    = (const float*)d_in[3];
    const float* bias = (const float*)d_in[4];
    const int*   pdm  = (const int*)d_in[5];
    const int*   ndm  = (const int*)d_in[6];
    float* out = (float*)d_out;

    unsigned short* Wt  = (unsigned short*)d_ws;          // [D][H] bf16, 192 KB
    unsigned short* emb = Wt + (size_t)H * D;             // [MTOT][D] bf16

    prep_w_kernel<<<(H * D + 255) / 256, 256, 0, stream>>>(W, Wt);
    proj_norm_kernel<<<MTOT / 128, 256, 0, stream>>>(qh, pdh, ndh, bias, pdm, ndm, Wt, emb);
    maxsim_kernel<<<Bsz * 2, 256, 0, stream>>>(emb, out);
}